// Round 15
// baseline (1831.037 us; speedup 1.0000x reference)
//
#include <hip/hip_runtime.h>
#include <hip/hip_bf16.h>

typedef float f32x4 __attribute__((ext_vector_type(4)));
typedef short s16x8 __attribute__((ext_vector_type(8)));
typedef unsigned long long ull;

#define NROWS 8192
#define MCOLS 8192
#define DIM   128
#define JSPLIT 16
#define JCHUNK 512   // cols per flash block
#define KVB    64    // cols per iteration
#define ITERS  8     // JCHUNK / KVB
#define PACKB  128   // pack-role blocks
#define FLASHB 1024  // 64 row-tiles x 16 jc

typedef __attribute__((address_space(3))) unsigned int lds_u32;
typedef __attribute__((address_space(1))) unsigned int g_u32;

__device__ __forceinline__ void gl_lds16(const void* g, void* l) {
    __builtin_amdgcn_global_load_lds((const g_u32*)g, (lds_u32*)l, 16, 0, 0);
}

// ---- prep: row-norm bf16 Q/K + Vt transpose ----
__global__ __launch_bounds__(256) void prep15(const float* __restrict__ xi,
                                              const float* __restrict__ xj,
                                              const float* __restrict__ beta,
                                              __hip_bfloat16* __restrict__ Qbf,
                                              __hip_bfloat16* __restrict__ Kbf,
                                              __hip_bfloat16* __restrict__ Vt) {
    __shared__ float tile[64][65];
    const int tid  = threadIdx.x;
    const int w    = tid >> 6;
    const int lane = tid & 63;
    {
        float b = beta[0];
#pragma unroll
        for (int sub = 0; sub < 2; ++sub) {
            int gr = blockIdx.x * 8 + w * 2 + sub;   // 0..16383
            const float* src;
            __hip_bfloat16* dst;
            int row;
            if (gr < NROWS) { row = gr;          src = xi; dst = Qbf; }
            else            { row = gr - NROWS;  src = xj; dst = Kbf; }
            const float* xr = src + (size_t)row * DIM;
            float x0 = xr[lane], x1 = xr[lane + 64];
            float ss = x0 * x0 + x1 * x1;
#pragma unroll
            for (int off = 32; off >= 1; off >>= 1) ss += __shfl_xor(ss, off);
            float s = 1.0f / sqrtf(ss);
            if (gr < NROWS) s *= b;
            __hip_bfloat16* o = dst + (size_t)row * DIM;
            o[lane]      = __float2bfloat16(x0 * s);
            o[lane + 64] = __float2bfloat16(x1 * s);
        }
    }
    if (blockIdx.x < 256) {
        int j0 = (blockIdx.x & 127) * 64;
        int d0 = (blockIdx.x >> 7) * 64;
#pragma unroll
        for (int c = 0; c < 16; ++c) {
            int idx = tid + 256 * c;
            int jr = idx >> 6, dc = idx & 63;
            tile[jr][dc] = xj[(size_t)(j0 + jr) * DIM + d0 + dc];
        }
        __syncthreads();
#pragma unroll
        for (int c = 0; c < 16; ++c) {
            int idx = tid + 256 * c;
            int dr = idx >> 6, jc = idx & 63;
            Vt[(size_t)(d0 + dr) * MCOLS + j0 + jc] = __float2bfloat16(tile[jc][dr]);
        }
    }
}

// ---- fused: pack-role blocks stream adj->bm (agent atomics + release flags)
//      while flash-role blocks (round-10 body, proven) consume per-row flags.
//      Idempotent self-pack fallback on timeout -> deadlock-free under any
//      dispatch order. bm layout: bm[row*128 + wix] bit l = adj[row][wix*64+l].
__global__ __launch_bounds__(256, 2) void fused15(const __hip_bfloat16* __restrict__ Qbf,
                                                  const __hip_bfloat16* __restrict__ Kbf,
                                                  const __hip_bfloat16* __restrict__ Vt,
                                                  const int* __restrict__ adj,
                                                  ull* bm, unsigned int* prog,
                                                  float* __restrict__ Opart,
                                                  float* __restrict__ Lpart) {
    __shared__ char smem[81920];
    const int tid  = threadIdx.x;
    const int w    = tid >> 6;
    const int lane = tid & 63;

    if (blockIdx.x < PACKB) {
        // ---- pack role: superstep ss covers rows ss*256..ss*256+255 ----
        const int gw2 = blockIdx.x * 4 + w;          // 0..511
        for (int ss = 0; ss < 32; ++ss) {
            int a[16][4];
#pragma unroll
            for (int k = 0; k < 16; ++k) {
                const int win = ss * 8192 + k * 512 + gw2;   // window = 256 cols of row win>>5
                const int* base = adj + (size_t)win * 256;
#pragma unroll
                for (int q = 0; q < 4; ++q) a[k][q] = base[q * 64 + lane];
            }
#pragma unroll
            for (int k = 0; k < 16; ++k) {
                const int win = ss * 8192 + k * 512 + gw2;
                ull b0 = __ballot(a[k][0] != 0);
                ull b1 = __ballot(a[k][1] != 0);
                ull b2 = __ballot(a[k][2] != 0);
                ull b3 = __ballot(a[k][3] != 0);
                if (lane < 4) {
                    ull v = lane == 0 ? b0 : (lane == 1 ? b1 : (lane == 2 ? b2 : b3));
                    __hip_atomic_store(bm + (size_t)win * 4 + lane, v,
                                       __ATOMIC_RELAXED, __HIP_MEMORY_SCOPE_AGENT);
                }
            }
            if (lane == 0)
                __hip_atomic_fetch_add(prog + ss, 1u, __ATOMIC_RELEASE, __HIP_MEMORY_SCOPE_AGENT);
        }
        return;
    }

    // ---- flash role (round-10 flash10 body, JSPLIT=16) ----
    const int fbid = (int)blockIdx.x - PACKB;
    const int jc   = fbid & (JSPLIT - 1);
    const int rt   = fbid >> 4;            // 0..63
    const int g    = lane >> 4;
    const int ln   = lane & 15;
    const int wra  = rt * 128 + w * 32;
    const int jbase = jc * JCHUNK;
    const int lx   = ln & 7;

    // wait for masks of rows [rt*128, rt*128+128) = flag rt>>1 (512 waves)
    {
        int ok = 1;
        if (lane == 0) {
            int polls = 0;
            while (__hip_atomic_load(prog + (rt >> 1), __ATOMIC_RELAXED,
                                     __HIP_MEMORY_SCOPE_AGENT) < 512u) {
                __builtin_amdgcn_s_sleep(32);
                if (++polls > 256) { ok = 0; break; }
            }
        }
        ok = __shfl(ok, 0);
        if (!ok) {
            // idempotent self-pack of this wave's 32 rows (adversarial-dispatch only)
            const int wr0 = wra;
            for (int i = 0; i < 1024; ++i) {       // 32 rows x 32 col-windows
                const int win = (wr0 + (i >> 5)) * 32 + (i & 31);
                const int* base = adj + (size_t)win * 256;
                int a0 = base[lane], a1 = base[64 + lane], a2 = base[128 + lane], a3 = base[192 + lane];
                ull b0 = __ballot(a0 != 0), b1 = __ballot(a1 != 0);
                ull b2 = __ballot(a2 != 0), b3 = __ballot(a3 != 0);
                if (lane < 4) {
                    ull v = lane == 0 ? b0 : (lane == 1 ? b1 : (lane == 2 ? b2 : b3));
                    __hip_atomic_store(bm + (size_t)win * 4 + lane, v,
                                       __ATOMIC_RELAXED, __HIP_MEMORY_SCOPE_AGENT);
                }
            }
            asm volatile("s_waitcnt vmcnt(0)" ::: "memory");
        }
        __builtin_amdgcn_fence(__ATOMIC_ACQUIRE, "agent");
    }

    s16x8 qf[2][4];
#pragma unroll
    for (int ti = 0; ti < 2; ++ti)
#pragma unroll
        for (int kt = 0; kt < 4; ++kt)
            qf[ti][kt] = *(const s16x8*)(Qbf + (size_t)(wra + ti * 16 + ln) * DIM + kt * 32 + g * 8);

    f32x4 zero = {0.f, 0.f, 0.f, 0.f};
    f32x4 acc[2][8];
#pragma unroll
    for (int ti = 0; ti < 2; ++ti)
#pragma unroll
        for (int dt = 0; dt < 8; ++dt) acc[ti][dt] = zero;
    float lr[2][4] = {{0.f, 0.f, 0.f, 0.f}, {0.f, 0.f, 0.f, 0.f}};

    char* pw = smem + 65536 + w * 4096;

    auto STAGE = [&](int jt, int b) {
        char* kb = smem + b * 16384;
        char* vb = smem + 32768 + b * 16384;
#pragma unroll
        for (int p = 0; p < 4; ++p) {
            int S = p * 256 + tid;
            int row = S >> 4, u = S & 15;
            gl_lds16((const char*)Kbf + (((size_t)(jt + row)) << 8) + ((u ^ (row & 7)) << 4),
                     kb + p * 4096 + w * 1024);
        }
#pragma unroll
        for (int p = 0; p < 4; ++p) {
            int S = p * 256 + tid;
            int row = S >> 3, u = S & 7;
            gl_lds16((const char*)Vt + (((size_t)row) << 14) + (((size_t)jt) << 1) + ((u ^ (row & 7)) << 4),
                     vb + p * 4096 + w * 1024);
        }
    };

    STAGE(jbase, 0);
    __syncthreads();
    int cur = 0;

    for (int it = 0; it < ITERS; ++it) {
        const int jt = jbase + it * KVB;

        ull mw[2][4];
#pragma unroll
        for (int ti = 0; ti < 2; ++ti)
#pragma unroll
            for (int r = 0; r < 4; ++r)
                mw[ti][r] = bm[(size_t)(wra + ti * 16 + g * 4 + r) * 128 + (jt >> 6)];
        __builtin_amdgcn_sched_barrier(0);

        STAGE(jbase + ((it + 1) & (ITERS - 1)) * KVB, cur ^ 1);

        const char* kb = smem + cur * 16384;
        const char* vb = smem + 32768 + cur * 16384;

        f32x4 s4[2][4];
#pragma unroll
        for (int ti = 0; ti < 2; ++ti)
#pragma unroll
            for (int ct = 0; ct < 4; ++ct) s4[ti][ct] = zero;
#pragma unroll
        for (int ct = 0; ct < 4; ++ct)
#pragma unroll
            for (int kt = 0; kt < 4; ++kt) {
                s16x8 kf = *(const s16x8*)(kb + (ct * 16 + ln) * 256 + (((kt * 4 + g) ^ lx) << 4));
                s4[0][ct] = __builtin_amdgcn_mfma_f32_16x16x32_bf16(qf[0][kt], kf, s4[0][ct], 0, 0, 0);
                s4[1][ct] = __builtin_amdgcn_mfma_f32_16x16x32_bf16(qf[1][kt], kf, s4[1][ct], 0, 0, 0);
            }

#pragma unroll
        for (int ti = 0; ti < 2; ++ti)
#pragma unroll
            for (int r = 0; r < 4; ++r) {
                const int row = g * 4 + r;
                const int rs = row & 7;
#pragma unroll
                for (int ct = 0; ct < 4; ++ct) {
                    float p = ((mw[ti][r] >> (ct * 16 + ln)) & 1) ? __expf(s4[ti][ct][r]) : 0.f;
                    lr[ti][r] += p;
                    *(__hip_bfloat16*)(pw + ti * 2048 + row * 128 +
                                       (((ct * 2 + (ln >> 3)) ^ rs) << 4) + (ln & 7) * 2)
                        = __float2bfloat16(p);
                }
            }

#pragma unroll
        for (int kt2 = 0; kt2 < 2; ++kt2) {
            const int uo = ((kt2 * 4 + g) ^ lx) << 4;
            s16x8 pf0 = *(const s16x8*)(pw + ln * 128 + uo);
            s16x8 pf1 = *(const s16x8*)(pw + 2048 + ln * 128 + uo);
#pragma unroll
            for (int dt = 0; dt < 8; ++dt) {
                s16x8 vf = *(const s16x8*)(vb + (dt * 16 + ln) * 128 + uo);
                acc[0][dt] = __builtin_amdgcn_mfma_f32_16x16x32_bf16(pf0, vf, acc[0][dt], 0, 0, 0);
                acc[1][dt] = __builtin_amdgcn_mfma_f32_16x16x32_bf16(pf1, vf, acc[1][dt], 0, 0, 0);
            }
        }

        __syncthreads();
        cur ^= 1;
    }

#pragma unroll
    for (int ti = 0; ti < 2; ++ti)
#pragma unroll
        for (int r = 0; r < 4; ++r) {
            lr[ti][r] += __shfl_xor(lr[ti][r], 1);
            lr[ti][r] += __shfl_xor(lr[ti][r], 2);
            lr[ti][r] += __shfl_xor(lr[ti][r], 4);
            lr[ti][r] += __shfl_xor(lr[ti][r], 8);
        }

#pragma unroll
    for (int ti = 0; ti < 2; ++ti) {
        float* ob = Opart + ((size_t)jc * NROWS + wra + ti * 16 + g * 4) * DIM;
#pragma unroll
        for (int r = 0; r < 4; ++r)
#pragma unroll
            for (int dt = 0; dt < 8; ++dt)
                ob[(size_t)r * DIM + dt * 16 + ln] = acc[ti][dt][r];
        if (ln == 0) {
#pragma unroll
            for (int r = 0; r < 4; ++r)
                Lpart[(size_t)jc * NROWS + wra + ti * 16 + g * 4 + r] = lr[ti][r];
        }
    }
}

// ---- merge: out[row][d] = sum_jc Op / sum_jc L ----
__global__ __launch_bounds__(256) void merge15(const float* __restrict__ Opart,
                                               const float* __restrict__ Lpart,
                                               float* __restrict__ out) {
    int gid = blockIdx.x * 256 + threadIdx.x;
    int row = gid >> 5;
    int dq  = (gid & 31) * 4;
    float4 sum = {0.f, 0.f, 0.f, 0.f};
    float L = 0.f;
#pragma unroll
    for (int jc = 0; jc < JSPLIT; ++jc) {
        float4 v = *(const float4*)(Opart + ((size_t)jc * NROWS + row) * DIM + dq);
        sum.x += v.x; sum.y += v.y; sum.z += v.z; sum.w += v.w;
        L += Lpart[(size_t)jc * NROWS + row];
    }
    float inv = 1.0f / fmaxf(L, 1e-37f);
    float4 ov = {sum.x * inv, sum.y * inv, sum.z * inv, sum.w * inv};
    *(float4*)(out + (size_t)row * DIM + dq) = ov;
}

extern "C" void kernel_launch(void* const* d_in, const int* in_sizes, int n_in,
                              void* d_out, int out_size, void* d_ws, size_t ws_size,
                              hipStream_t stream) {
    const float* xi   = (const float*)d_in[0];
    const float* xj   = (const float*)d_in[1];
    const int*   adj  = (const int*)d_in[2];
    const float* beta = (const float*)d_in[3];
    float* out = (float*)d_out;

    char* ws = (char*)d_ws;
    __hip_bfloat16* Qbf = (__hip_bfloat16*)ws;                                  // @0,  2 MiB
    __hip_bfloat16* Kbf = (__hip_bfloat16*)(ws + (2u << 20));                   // @2M, 2 MiB
    __hip_bfloat16* Vt  = (__hip_bfloat16*)(ws + (4u << 20));                   // @4M, 2 MiB
    ull*            bm  = (ull*)(ws + (6u << 20));                              // @6M, 8 MiB
    unsigned int*  prog = (unsigned int*)(ws + (14u << 20));                    // @14M, 128 B
    float*          Op  = (float*)(ws + (16u << 20));                           // @16M, 64 MiB
    float*          Lp  = (float*)(ws + (80u << 20));                           // @80M, 512 KiB

    hipMemsetAsync(prog, 0, 32 * sizeof(unsigned int), stream);
    hipLaunchKernelGGL(prep15, dim3(2048), dim3(256), 0, stream, xi, xj, beta, Qbf, Kbf, Vt);
    hipLaunchKernelGGL(fused15, dim3(PACKB + FLASHB), dim3(256), 0, stream,
                       Qbf, Kbf, Vt, adj, bm, prog, Op, Lp);
    hipLaunchKernelGGL(merge15, dim3(1024), dim3(256), 0, stream, Op, Lp, out);
}

// Round 16
// 135.243 us; speedup vs baseline: 13.5389x; 13.5389x over previous
//
#include <hip/hip_runtime.h>
#include <hip/hip_bf16.h>

typedef float f32x4 __attribute__((ext_vector_type(4)));
typedef short s16x8 __attribute__((ext_vector_type(8)));
typedef unsigned long long ull;

#define NROWS 8192
#define MCOLS 8192
#define DIM   128
#define JSPLIT 16
#define JCHUNK 512   // cols per block
#define KVB    32    // cols per iteration
#define ITERS  16    // JCHUNK / KVB

typedef __attribute__((address_space(3))) unsigned int lds_u32;
typedef __attribute__((address_space(1))) unsigned int g_u32;

__device__ __forceinline__ void gl_lds16(const void* g, void* l) {
    __builtin_amdgcn_global_load_lds((const g_u32*)g, (lds_u32*)l, 16, 0, 0);
}

// ---- fused prep: adj bit-pack (grid-contiguous stream) + row-norm bf16 Q/K +
//      Vt transpose (identical to the round-10 version) ----
__global__ __launch_bounds__(256) void prep_all(const float* __restrict__ xi,
                                                const float* __restrict__ xj,
                                                const float* __restrict__ beta,
                                                const int* __restrict__ adj,
                                                __hip_bfloat16* __restrict__ Qbf,
                                                __hip_bfloat16* __restrict__ Kbf,
                                                __hip_bfloat16* __restrict__ Vt,
                                                ull* __restrict__ bm) {
    __shared__ float tile[64][65];
    const int tid  = threadIdx.x;
    const int w    = tid >> 6;
    const int lane = tid & 63;

    {
        float b = beta[0];
#pragma unroll
        for (int sub = 0; sub < 2; ++sub) {
            int gr = blockIdx.x * 8 + w * 2 + sub;   // 0..16383
            const float* src;
            __hip_bfloat16* dst;
            int row;
            if (gr < NROWS) { row = gr;          src = xi; dst = Qbf; }
            else            { row = gr - NROWS;  src = xj; dst = Kbf; }
            const float* xr = src + (size_t)row * DIM;
            float x0 = xr[lane], x1 = xr[lane + 64];
            float ss = x0 * x0 + x1 * x1;
#pragma unroll
            for (int off = 32; off >= 1; off >>= 1) ss += __shfl_xor(ss, off);
            float s = 1.0f / sqrtf(ss);
            if (gr < NROWS) s *= b;
            __hip_bfloat16* o = dst + (size_t)row * DIM;
            o[lane]      = __float2bfloat16(x0 * s);
            o[lane + 64] = __float2bfloat16(x1 * s);
        }
    }

    if (blockIdx.x < 256) {
        int j0 = (blockIdx.x & 127) * 64;
        int d0 = (blockIdx.x >> 7) * 64;
#pragma unroll
        for (int c = 0; c < 16; ++c) {
            int idx = tid + 256 * c;
            int jr = idx >> 6, dc = idx & 63;
            tile[jr][dc] = xj[(size_t)(j0 + jr) * DIM + d0 + dc];
        }
        __syncthreads();
#pragma unroll
        for (int c = 0; c < 16; ++c) {
            int idx = tid + 256 * c;
            int dr = idx >> 6, jc = idx & 63;
            Vt[(size_t)(d0 + dr) * MCOLS + j0 + jc] = __float2bfloat16(tile[jc][dr]);
        }
        __syncthreads();
    }

    // adj pack: window = 256 cols of one row; 8MB contiguous per grid step.
    const int gw = (int)((blockIdx.x * 256 + tid) >> 6); // 0..8191
#pragma unroll 2
    for (int s = 0; s < 32; ++s) {
        int win = gw + s * 8192;
        const int* base = adj + (size_t)win * 256;
        int a0 = base[lane], a1 = base[64 + lane], a2 = base[128 + lane], a3 = base[192 + lane];
        ull b0 = __ballot(a0 != 0);
        ull b1 = __ballot(a1 != 0);
        ull b2 = __ballot(a2 != 0);
        ull b3 = __ballot(a3 != 0);
        if (lane < 4) {
            ull v = (lane == 0) ? b0 : ((lane == 1) ? b1 : ((lane == 2) ? b2 : b3));
            bm[(size_t)win * 4 + lane] = v;
        }
    }
}

// ---- flash16: round-10 body at KVB=32 / JSPLIT=16. LDS = 40KB -> up to
//      4 blocks/CU (16 waves/CU): finer barriers interleave across blocks.
//      Wave owns 32 rows (2x16 tiles); K/V fragments feed both tiles.
//      Plain-sum softmax (|score| <= beta < 1). ----
__global__ __launch_bounds__(256) void flash16(const __hip_bfloat16* __restrict__ Qbf,
                                               const __hip_bfloat16* __restrict__ Kbf,
                                               const __hip_bfloat16* __restrict__ Vt,
                                               const ull* __restrict__ bm,
                                               float* __restrict__ Opart,
                                               float* __restrict__ Lpart) {
    // LDS: K[2][32][128]bf16 (2x8K) | V[2][128][32]bf16 @16384 (2x8K)
    //      P: 4 waves x 2 tiles x [16][32] swz @32768 (8K). Total 40K.
    __shared__ char smem[40960];

    const int tid  = threadIdx.x;
    const int w    = tid >> 6;
    const int lane = tid & 63;
    const int g    = lane >> 4;
    const int ln   = lane & 15;
    const int bid  = blockIdx.x;
    const int jc   = bid & (JSPLIT - 1);
    const int rt   = bid >> 4;            // 0..63
    const int wra  = rt * 128 + w * 32;   // wave's first row (2 tiles of 16)
    const int jbase = jc * JCHUNK;
    const int lx   = ln & 7;
    const int swv  = (ln & 3) ^ ((ln >> 2) & 3);   // V/P read-side XOR

    s16x8 qf[2][4];
#pragma unroll
    for (int ti = 0; ti < 2; ++ti)
#pragma unroll
        for (int kt = 0; kt < 4; ++kt)
            qf[ti][kt] = *(const s16x8*)(Qbf + (size_t)(wra + ti * 16 + ln) * DIM + kt * 32 + g * 8);

    f32x4 zero = {0.f, 0.f, 0.f, 0.f};
    f32x4 acc[2][8];
#pragma unroll
    for (int ti = 0; ti < 2; ++ti)
#pragma unroll
        for (int dt = 0; dt < 8; ++dt) acc[ti][dt] = zero;
    float lr[2][4] = {{0.f, 0.f, 0.f, 0.f}, {0.f, 0.f, 0.f, 0.f}};

    char* pw = smem + 32768 + w * 2048;   // P: 2 tiles x 1KB, swizzled

    auto STAGE = [&](int jt, int b) {
        char* kb = smem + b * 8192;
        char* vb = smem + 16384 + b * 8192;
        // K tile [32 j][128 d]: 512 units, src col-unit = u ^ (row&7)
#pragma unroll
        for (int p = 0; p < 2; ++p) {
            int S = p * 256 + tid;
            int row = S >> 4, u = S & 15;
            gl_lds16((const char*)Kbf + (((size_t)(jt + row)) << 8) + ((u ^ (row & 7)) << 4),
                     kb + p * 4096 + w * 1024);
        }
        // V tile [128 d][32 j]: 512 units (4/row), src unit = u ^ ((row&3)^((row>>2)&3))
#pragma unroll
        for (int p = 0; p < 2; ++p) {
            int S = p * 256 + tid;
            int row = S >> 2, u = S & 3;
            int sw = (row & 3) ^ ((row >> 2) & 3);
            gl_lds16((const char*)Vt + (((size_t)row) << 14) + (((size_t)jt) << 1) + ((u ^ sw) << 4),
                     vb + p * 4096 + w * 1024);
        }
    };

    STAGE(jbase, 0);
    __syncthreads();
    int cur = 0;

    for (int it = 0; it < ITERS; ++it) {
        const int jt = jbase + it * KVB;

        // mask words (2 tiles x 4 rows); cols jt..jt+31 live in bits (jt&32)+..
        ull mw[2][4];
#pragma unroll
        for (int ti = 0; ti < 2; ++ti)
#pragma unroll
            for (int r = 0; r < 4; ++r)
                mw[ti][r] = bm[(size_t)(wra + ti * 16 + g * 4 + r) * 128 + (jt >> 6)];
        __builtin_amdgcn_sched_barrier(0);

        STAGE(jbase + ((it + 1) & (ITERS - 1)) * KVB, cur ^ 1);

        const char* kb = smem + cur * 8192;
        const char* vb = smem + 16384 + cur * 8192;

        // QK: S[16 rows][32 cols] per tile; kf feeds both row tiles
        f32x4 s4[2][2];
#pragma unroll
        for (int ti = 0; ti < 2; ++ti)
#pragma unroll
            for (int ct = 0; ct < 2; ++ct) s4[ti][ct] = zero;
#pragma unroll
        for (int ct = 0; ct < 2; ++ct)
#pragma unroll
            for (int kt = 0; kt < 4; ++kt) {
                s16x8 kf = *(const s16x8*)(kb + (ct * 16 + ln) * 256 + (((kt * 4 + g) ^ lx) << 4));
                s4[0][ct] = __builtin_amdgcn_mfma_f32_16x16x32_bf16(qf[0][kt], kf, s4[0][ct], 0, 0, 0);
                s4[1][ct] = __builtin_amdgcn_mfma_f32_16x16x32_bf16(qf[1][kt], kf, s4[1][ct], 0, 0, 0);
            }

        // softmax-lite: p = adj ? exp(s) : 0; P -> swizzled LDS [16][4 units]
        const int bbase = jt & 32;
#pragma unroll
        for (int ti = 0; ti < 2; ++ti)
#pragma unroll
            for (int r = 0; r < 4; ++r) {
                const int row = g * 4 + r;
                const int rs = r ^ g;     // (row&3)^((row>>2)&3)
#pragma unroll
                for (int ct = 0; ct < 2; ++ct) {
                    float p = ((mw[ti][r] >> (bbase + ct * 16 + ln)) & 1) ? __expf(s4[ti][ct][r]) : 0.f;
                    lr[ti][r] += p;
                    *(__hip_bfloat16*)(pw + ti * 1024 + row * 64 +
                                       (((ct * 2 + (ln >> 3)) ^ rs) << 4) + (ln & 7) * 2)
                        = __float2bfloat16(p);
                }
            }

        // PV: k=32 -> one pf b128 per tile; vf feeds both tiles
#pragma unroll
        for (int ti = 0; ti < 2; ++ti) {
            s16x8 pf = *(const s16x8*)(pw + ti * 1024 + ln * 64 + ((g ^ swv) << 4));
#pragma unroll
            for (int dt = 0; dt < 8; ++dt) {
                s16x8 vf = *(const s16x8*)(vb + (dt * 16 + ln) * 64 + ((g ^ swv) << 4));
                acc[ti][dt] = __builtin_amdgcn_mfma_f32_16x16x32_bf16(pf, vf, acc[ti][dt], 0, 0, 0);
            }
        }

        __syncthreads();
        cur ^= 1;
    }

    // row sums within 16-lane group
#pragma unroll
    for (int ti = 0; ti < 2; ++ti)
#pragma unroll
        for (int r = 0; r < 4; ++r) {
            lr[ti][r] += __shfl_xor(lr[ti][r], 1);
            lr[ti][r] += __shfl_xor(lr[ti][r], 2);
            lr[ti][r] += __shfl_xor(lr[ti][r], 4);
            lr[ti][r] += __shfl_xor(lr[ti][r], 8);
        }

    // write partials
#pragma unroll
    for (int ti = 0; ti < 2; ++ti) {
        float* ob = Opart + ((size_t)jc * NROWS + wra + ti * 16 + g * 4) * DIM;
#pragma unroll
        for (int r = 0; r < 4; ++r)
#pragma unroll
            for (int dt = 0; dt < 8; ++dt)
                ob[(size_t)r * DIM + dt * 16 + ln] = acc[ti][dt][r];
        if (ln == 0) {
#pragma unroll
            for (int r = 0; r < 4; ++r)
                Lpart[(size_t)jc * NROWS + wra + ti * 16 + g * 4 + r] = lr[ti][r];
        }
    }
}

// ---- merge: out[row][d] = sum_jc Op / sum_jc L ----
__global__ __launch_bounds__(256) void merge16(const float* __restrict__ Opart,
                                               const float* __restrict__ Lpart,
                                               float* __restrict__ out) {
    int gid = blockIdx.x * 256 + threadIdx.x;
    int row = gid >> 5;
    int dq  = (gid & 31) * 4;
    float4 sum = {0.f, 0.f, 0.f, 0.f};
    float L = 0.f;
#pragma unroll
    for (int jc = 0; jc < JSPLIT; ++jc) {
        float4 v = *(const float4*)(Opart + ((size_t)jc * NROWS + row) * DIM + dq);
        sum.x += v.x; sum.y += v.y; sum.z += v.z; sum.w += v.w;
        L += Lpart[(size_t)jc * NROWS + row];
    }
    float inv = 1.0f / fmaxf(L, 1e-37f);
    float4 ov = {sum.x * inv, sum.y * inv, sum.z * inv, sum.w * inv};
    *(float4*)(out + (size_t)row * DIM + dq) = ov;
}

extern "C" void kernel_launch(void* const* d_in, const int* in_sizes, int n_in,
                              void* d_out, int out_size, void* d_ws, size_t ws_size,
                              hipStream_t stream) {
    const float* xi   = (const float*)d_in[0];
    const float* xj   = (const float*)d_in[1];
    const int*   adj  = (const int*)d_in[2];
    const float* beta = (const float*)d_in[3];
    float* out = (float*)d_out;

    char* ws = (char*)d_ws;
    __hip_bfloat16* Qbf = (__hip_bfloat16*)ws;                                    // @0,   2 MiB
    __hip_bfloat16* Kbf = (__hip_bfloat16*)(ws + (2u << 20));                     // @2M,  2 MiB
    __hip_bfloat16* Vt  = (__hip_bfloat16*)(ws + (4u << 20));                     // @4M,  2 MiB
    ull*            bm  = (ull*)(ws + (6u << 20));                                // @6M,  8 MiB
    float*          Op  = (float*)(ws + (14u << 20));                             // @14M, 64 MiB
    float*          Lp  = (float*)(ws + (78u << 20));                             // @78M, 512 KiB

    hipLaunchKernelGGL(prep_all, dim3(2048), dim3(256), 0, stream, xi, xj, beta, adj, Qbf, Kbf, Vt, bm);
    hipLaunchKernelGGL(flash16, dim3(64 * JSPLIT), dim3(256), 0, stream, Qbf, Kbf, Vt, bm, Op, Lp);
    hipLaunchKernelGGL(merge16, dim3(1024), dim3(256), 0, stream, Op, Lp, out);
}

// Round 17
// 118.520 us; speedup vs baseline: 15.4492x; 1.1411x over previous
//
#include <hip/hip_runtime.h>
#include <hip/hip_bf16.h>

typedef float f32x4 __attribute__((ext_vector_type(4)));
typedef short s16x8 __attribute__((ext_vector_type(8)));
typedef unsigned long long ull;

#define NROWS 8192
#define MCOLS 8192
#define DIM   128
#define JSPLIT 8
#define JCHUNK 1024  // cols per block
#define KVB    64    // cols per iteration
#define ITERS  16    // JCHUNK / KVB

typedef __attribute__((address_space(3))) unsigned int lds_u32;
typedef __attribute__((address_space(1))) unsigned int g_u32;

__device__ __forceinline__ void gl_lds16(const void* g, void* l) {
    __builtin_amdgcn_global_load_lds((const g_u32*)g, (lds_u32*)l, 16, 0, 0);
}

// ---- fused prep: adj bit-pack (grid-contiguous stream, dominates) +
//      row-norm bf16 Q/K (hidden under stream) + Vt transpose (blocks<256) ----
__global__ __launch_bounds__(256) void prep_all(const float* __restrict__ xi,
                                                const float* __restrict__ xj,
                                                const float* __restrict__ beta,
                                                const int* __restrict__ adj,
                                                __hip_bfloat16* __restrict__ Qbf,
                                                __hip_bfloat16* __restrict__ Kbf,
                                                __hip_bfloat16* __restrict__ Vt,
                                                ull* __restrict__ bm) {
    __shared__ float tile[64][65];
    const int tid  = threadIdx.x;
    const int w    = tid >> 6;
    const int lane = tid & 63;

    // row norms, 8 rows per block (2 per wave)
    {
        float b = beta[0];
#pragma unroll
        for (int sub = 0; sub < 2; ++sub) {
            int gr = blockIdx.x * 8 + w * 2 + sub;   // 0..16383
            const float* src;
            __hip_bfloat16* dst;
            int row;
            if (gr < NROWS) { row = gr;          src = xi; dst = Qbf; }
            else            { row = gr - NROWS;  src = xj; dst = Kbf; }
            const float* xr = src + (size_t)row * DIM;
            float x0 = xr[lane], x1 = xr[lane + 64];
            float ss = x0 * x0 + x1 * x1;
#pragma unroll
            for (int off = 32; off >= 1; off >>= 1) ss += __shfl_xor(ss, off);
            float s = 1.0f / sqrtf(ss);
            if (gr < NROWS) s *= b;
            __hip_bfloat16* o = dst + (size_t)row * DIM;
            o[lane]      = __float2bfloat16(x0 * s);
            o[lane + 64] = __float2bfloat16(x1 * s);
        }
    }

    // Vt transpose (raw xj), one 64x64 tile for blocks < 256
    if (blockIdx.x < 256) {
        int j0 = (blockIdx.x & 127) * 64;
        int d0 = (blockIdx.x >> 7) * 64;
#pragma unroll
        for (int c = 0; c < 16; ++c) {
            int idx = tid + 256 * c;
            int jr = idx >> 6, dc = idx & 63;
            tile[jr][dc] = xj[(size_t)(j0 + jr) * DIM + d0 + dc];
        }
        __syncthreads();
#pragma unroll
        for (int c = 0; c < 16; ++c) {
            int idx = tid + 256 * c;
            int dr = idx >> 6, jc = idx & 63;
            Vt[(size_t)(d0 + dr) * MCOLS + j0 + jc] = __float2bfloat16(tile[jc][dr]);
        }
        __syncthreads();
    }

    // adj pack: window = 256 cols of one row; 8MB contiguous per grid step.
    const int gw = (int)((blockIdx.x * 256 + tid) >> 6); // 0..8191
#pragma unroll 2
    for (int s = 0; s < 32; ++s) {
        int win = gw + s * 8192;
        const int* base = adj + (size_t)win * 256;
        int a0 = base[lane], a1 = base[64 + lane], a2 = base[128 + lane], a3 = base[192 + lane];
        ull b0 = __ballot(a0 != 0);
        ull b1 = __ballot(a1 != 0);
        ull b2 = __ballot(a2 != 0);
        ull b3 = __ballot(a3 != 0);
        if (lane < 4) {
            ull v = (lane == 0) ? b0 : ((lane == 1) ? b1 : ((lane == 2) ? b2 : b3));
            bm[(size_t)win * 4 + lane] = v;
        }
    }
}

// ---- flash17: round-10 flash10 body + mask words pipelined 1 tile deep in
//      registers (removes the mid-iter vmcnt wait on the L3-resident bm).
//      Per iter: issue mask(t+1)->mwn, STAGE(t+1), QK(t), softmax(t) w/ mwc
//      (already in regs), PV(t), barrier, rotate. LDS exactly 80KB -> 2/CU.
//      Plain-sum softmax (|score| <= beta < 1 -> p = adj ? exp(s) : 0). ----
__global__ __launch_bounds__(256, 2) void flash17(const __hip_bfloat16* __restrict__ Qbf,
                                                  const __hip_bfloat16* __restrict__ Kbf,
                                                  const __hip_bfloat16* __restrict__ Vt,
                                                  const ull* __restrict__ bm,
                                                  float* __restrict__ Opart,
                                                  float* __restrict__ Lpart) {
    // LDS: K[2][64][128]bf16 (2x16K) | V[2][128][64]bf16 @32768 (2x16K)
    //      P: 4 waves x 2 tiles x [16][64] swizzled @65536 (16K). Total 80K.
    __shared__ char smem[81920];

    const int tid  = threadIdx.x;
    const int w    = tid >> 6;
    const int lane = tid & 63;
    const int g    = lane >> 4;
    const int ln   = lane & 15;
    const int bid  = blockIdx.x;
    const int jc   = bid & (JSPLIT - 1);
    const int rt   = bid >> 3;            // 0..63
    const int wra  = rt * 128 + w * 32;   // wave's first row (2 tiles of 16)
    const int jbase = jc * JCHUNK;
    const int lx   = ln & 7;

    s16x8 qf[2][4];
#pragma unroll
    for (int ti = 0; ti < 2; ++ti)
#pragma unroll
        for (int kt = 0; kt < 4; ++kt)
            qf[ti][kt] = *(const s16x8*)(Qbf + (size_t)(wra + ti * 16 + ln) * DIM + kt * 32 + g * 8);

    f32x4 zero = {0.f, 0.f, 0.f, 0.f};
    f32x4 acc[2][8];
#pragma unroll
    for (int ti = 0; ti < 2; ++ti)
#pragma unroll
        for (int dt = 0; dt < 8; ++dt) acc[ti][dt] = zero;
    float lr[2][4] = {{0.f, 0.f, 0.f, 0.f}, {0.f, 0.f, 0.f, 0.f}};

    char* pw = smem + 65536 + w * 4096;

    auto STAGE = [&](int jt, int b) {
        char* kb = smem + b * 16384;
        char* vb = smem + 32768 + b * 16384;
#pragma unroll
        for (int p = 0; p < 4; ++p) {
            int S = p * 256 + tid;
            int row = S >> 4, u = S & 15;
            gl_lds16((const char*)Kbf + (((size_t)(jt + row)) << 8) + ((u ^ (row & 7)) << 4),
                     kb + p * 4096 + w * 1024);
        }
#pragma unroll
        for (int p = 0; p < 4; ++p) {
            int S = p * 256 + tid;
            int row = S >> 3, u = S & 7;
            gl_lds16((const char*)Vt + (((size_t)row) << 14) + (((size_t)jt) << 1) + ((u ^ (row & 7)) << 4),
                     vb + p * 4096 + w * 1024);
        }
    };

    // prologue: mask(0) into mwc; stage tile 0
    ull mwc[2][4], mwn[2][4];
#pragma unroll
    for (int ti = 0; ti < 2; ++ti)
#pragma unroll
        for (int r = 0; r < 4; ++r)
            mwc[ti][r] = bm[(size_t)(wra + ti * 16 + g * 4 + r) * 128 + (jbase >> 6)];
    STAGE(jbase, 0);
    __syncthreads();
    int cur = 0;

    for (int it = 0; it < ITERS; ++it) {
        const int jtn = jbase + ((it + 1) & (ITERS - 1)) * KVB;

        // mask words for NEXT tile (consumed next iter, after the barrier;
        // never waited on mid-iter)
#pragma unroll
        for (int ti = 0; ti < 2; ++ti)
#pragma unroll
            for (int r = 0; r < 4; ++r)
                mwn[ti][r] = bm[(size_t)(wra + ti * 16 + g * 4 + r) * 128 + (jtn >> 6)];
        __builtin_amdgcn_sched_barrier(0);

        // prefetch next K/V tile into the other buffer
        STAGE(jtn, cur ^ 1);

        const char* kb = smem + cur * 16384;
        const char* vb = smem + 32768 + cur * 16384;

        // QK: each kf fragment feeds both row tiles
        f32x4 s4[2][4];
#pragma unroll
        for (int ti = 0; ti < 2; ++ti)
#pragma unroll
            for (int ct = 0; ct < 4; ++ct) s4[ti][ct] = zero;
#pragma unroll
        for (int ct = 0; ct < 4; ++ct)
#pragma unroll
            for (int kt = 0; kt < 4; ++kt) {
                s16x8 kf = *(const s16x8*)(kb + (ct * 16 + ln) * 256 + (((kt * 4 + g) ^ lx) << 4));
                s4[0][ct] = __builtin_amdgcn_mfma_f32_16x16x32_bf16(qf[0][kt], kf, s4[0][ct], 0, 0, 0);
                s4[1][ct] = __builtin_amdgcn_mfma_f32_16x16x32_bf16(qf[1][kt], kf, s4[1][ct], 0, 0, 0);
            }

        // softmax-lite: p = adj ? exp(s) : 0 (mask already in registers)
#pragma unroll
        for (int ti = 0; ti < 2; ++ti)
#pragma unroll
            for (int r = 0; r < 4; ++r) {
                const int row = g * 4 + r;
                const int rs = row & 7;
#pragma unroll
                for (int ct = 0; ct < 4; ++ct) {
                    float p = ((mwc[ti][r] >> (ct * 16 + ln)) & 1) ? __expf(s4[ti][ct][r]) : 0.f;
                    lr[ti][r] += p;
                    *(__hip_bfloat16*)(pw + ti * 2048 + row * 128 +
                                       (((ct * 2 + (ln >> 3)) ^ rs) << 4) + (ln & 7) * 2)
                        = __float2bfloat16(p);
                }
            }

        // PV: each vf fragment feeds both row tiles (same-wave LDS RAW on P)
#pragma unroll
        for (int kt2 = 0; kt2 < 2; ++kt2) {
            const int uo = ((kt2 * 4 + g) ^ lx) << 4;
            s16x8 pf0 = *(const s16x8*)(pw + ln * 128 + uo);
            s16x8 pf1 = *(const s16x8*)(pw + 2048 + ln * 128 + uo);
#pragma unroll
            for (int dt = 0; dt < 8; ++dt) {
                s16x8 vf = *(const s16x8*)(vb + (dt * 16 + ln) * 128 + uo);
                acc[0][dt] = __builtin_amdgcn_mfma_f32_16x16x32_bf16(pf0, vf, acc[0][dt], 0, 0, 0);
                acc[1][dt] = __builtin_amdgcn_mfma_f32_16x16x32_bf16(pf1, vf, acc[1][dt], 0, 0, 0);
            }
        }

        __syncthreads();   // drains STAGE(t+1) + mask(t+1) (whole compute phase of cover)
        cur ^= 1;

        // rotate mask pipeline (values guaranteed arrived by the barrier)
#pragma unroll
        for (int ti = 0; ti < 2; ++ti)
#pragma unroll
            for (int r = 0; r < 4; ++r) mwc[ti][r] = mwn[ti][r];
    }

    // row sums within 16-lane group
#pragma unroll
    for (int ti = 0; ti < 2; ++ti)
#pragma unroll
        for (int r = 0; r < 4; ++r) {
            lr[ti][r] += __shfl_xor(lr[ti][r], 1);
            lr[ti][r] += __shfl_xor(lr[ti][r], 2);
            lr[ti][r] += __shfl_xor(lr[ti][r], 4);
            lr[ti][r] += __shfl_xor(lr[ti][r], 8);
        }

    // write partials
#pragma unroll
    for (int ti = 0; ti < 2; ++ti) {
        float* ob = Opart + ((size_t)jc * NROWS + wra + ti * 16 + g * 4) * DIM;
#pragma unroll
        for (int r = 0; r < 4; ++r)
#pragma unroll
            for (int dt = 0; dt < 8; ++dt)
                ob[(size_t)r * DIM + dt * 16 + ln] = acc[ti][dt][r];
        if (ln == 0) {
#pragma unroll
            for (int r = 0; r < 4; ++r)
                Lpart[(size_t)jc * NROWS + wra + ti * 16 + g * 4 + r] = lr[ti][r];
        }
    }
}

// ---- merge: out[row][d] = sum_jc Op / sum_jc L ----
__global__ __launch_bounds__(256) void merge17(const float* __restrict__ Opart,
                                               const float* __restrict__ Lpart,
                                               float* __restrict__ out) {
    int gid = blockIdx.x * 256 + threadIdx.x;
    int row = gid >> 5;
    int dq  = (gid & 31) * 4;
    float4 sum = {0.f, 0.f, 0.f, 0.f};
    float L = 0.f;
#pragma unroll
    for (int jc = 0; jc < JSPLIT; ++jc) {
        float4 v = *(const float4*)(Opart + ((size_t)jc * NROWS + row) * DIM + dq);
        sum.x += v.x; sum.y += v.y; sum.z += v.z; sum.w += v.w;
        L += Lpart[(size_t)jc * NROWS + row];
    }
    float inv = 1.0f / fmaxf(L, 1e-37f);
    float4 ov = {sum.x * inv, sum.y * inv, sum.z * inv, sum.w * inv};
    *(float4*)(out + (size_t)row * DIM + dq) = ov;
}

extern "C" void kernel_launch(void* const* d_in, const int* in_sizes, int n_in,
                              void* d_out, int out_size, void* d_ws, size_t ws_size,
                              hipStream_t stream) {
    const float* xi   = (const float*)d_in[0];
    const float* xj   = (const float*)d_in[1];
    const int*   adj  = (const int*)d_in[2];
    const float* beta = (const float*)d_in[3];
    float* out = (float*)d_out;

    char* ws = (char*)d_ws;
    __hip_bfloat16* Qbf = (__hip_bfloat16*)ws;                                    // 2 MiB
    __hip_bfloat16* Kbf = (__hip_bfloat16*)(ws + (size_t)NROWS * DIM * 2);        // 2 MiB
    __hip_bfloat16* Vt  = (__hip_bfloat16*)(ws + 2 * (size_t)NROWS * DIM * 2);    // 2 MiB
    ull*            bm  = (ull*)(ws + 3 * (size_t)NROWS * DIM * 2);               // 8 MiB
    float*          Op  = (float*)(ws + 3 * (size_t)NROWS * DIM * 2 + (size_t)NROWS * (MCOLS / 8)); // 32 MiB
    float*          Lp  = (float*)((char*)Op + (size_t)JSPLIT * NROWS * DIM * 4); // 256 KiB

    hipLaunchKernelGGL(prep_all, dim3(2048), dim3(256), 0, stream, xi, xj, beta, adj, Qbf, Kbf, Vt, bm);
    hipLaunchKernelGGL(flash17, dim3(64 * JSPLIT), dim3(256), 0, stream, Qbf, Kbf, Vt, bm, Op, Lp);
    hipLaunchKernelGGL(merge17, dim3(1024), dim3(256), 0, stream, Op, Lp, out);
}

// Round 18
// 112.042 us; speedup vs baseline: 16.3425x; 1.0578x over previous
//
#include <hip/hip_runtime.h>
#include <hip/hip_bf16.h>

typedef float f32x4 __attribute__((ext_vector_type(4)));
typedef short s16x8 __attribute__((ext_vector_type(8)));
typedef unsigned long long ull;

#define NROWS 8192
#define MCOLS 8192
#define DIM   128
#define JSPLIT 8
#define JCHUNK 1024  // cols per block
#define KVB    64    // cols per iteration
#define ITERS  16    // JCHUNK / KVB

typedef __attribute__((address_space(3))) unsigned int lds_u32;
typedef __attribute__((address_space(1))) unsigned int g_u32;

__device__ __forceinline__ void gl_lds16(const void* g, void* l) {
    __builtin_amdgcn_global_load_lds((const g_u32*)g, (lds_u32*)l, 16, 0, 0);
}

__device__ __forceinline__ float bf16_to_f32(short s) {
    return __uint_as_float(((unsigned)(unsigned short)s) << 16);
}

// ---- fused prep: adj bit-pack (grid-contiguous stream, dominates) +
//      row-norm bf16 Q/K (hidden under stream) + Vt transpose (blocks<256) ----
__global__ __launch_bounds__(256) void prep_all(const float* __restrict__ xi,
                                                const float* __restrict__ xj,
                                                const float* __restrict__ beta,
                                                const int* __restrict__ adj,
                                                __hip_bfloat16* __restrict__ Qbf,
                                                __hip_bfloat16* __restrict__ Kbf,
                                                __hip_bfloat16* __restrict__ Vt,
                                                ull* __restrict__ bm) {
    __shared__ float tile[64][65];
    const int tid  = threadIdx.x;
    const int w    = tid >> 6;
    const int lane = tid & 63;

    // row norms, 8 rows per block (2 per wave)
    {
        float b = beta[0];
#pragma unroll
        for (int sub = 0; sub < 2; ++sub) {
            int gr = blockIdx.x * 8 + w * 2 + sub;   // 0..16383
            const float* src;
            __hip_bfloat16* dst;
            int row;
            if (gr < NROWS) { row = gr;          src = xi; dst = Qbf; }
            else            { row = gr - NROWS;  src = xj; dst = Kbf; }
            const float* xr = src + (size_t)row * DIM;
            float x0 = xr[lane], x1 = xr[lane + 64];
            float ss = x0 * x0 + x1 * x1;
#pragma unroll
            for (int off = 32; off >= 1; off >>= 1) ss += __shfl_xor(ss, off);
            float s = 1.0f / sqrtf(ss);
            if (gr < NROWS) s *= b;
            __hip_bfloat16* o = dst + (size_t)row * DIM;
            o[lane]      = __float2bfloat16(x0 * s);
            o[lane + 64] = __float2bfloat16(x1 * s);
        }
    }

    // Vt transpose (raw xj), one 64x64 tile for blocks < 256
    if (blockIdx.x < 256) {
        int j0 = (blockIdx.x & 127) * 64;
        int d0 = (blockIdx.x >> 7) * 64;
#pragma unroll
        for (int c = 0; c < 16; ++c) {
            int idx = tid + 256 * c;
            int jr = idx >> 6, dc = idx & 63;
            tile[jr][dc] = xj[(size_t)(j0 + jr) * DIM + d0 + dc];
        }
        __syncthreads();
#pragma unroll
        for (int c = 0; c < 16; ++c) {
            int idx = tid + 256 * c;
            int dr = idx >> 6, jc = idx & 63;
            Vt[(size_t)(d0 + dr) * MCOLS + j0 + jc] = __float2bfloat16(tile[jc][dr]);
        }
        __syncthreads();
    }

    // adj pack: window = 256 cols of one row; 8MB contiguous per grid step.
    const int gw = (int)((blockIdx.x * 256 + tid) >> 6); // 0..8191
#pragma unroll 2
    for (int s = 0; s < 32; ++s) {
        int win = gw + s * 8192;
        const int* base = adj + (size_t)win * 256;
        int a0 = base[lane], a1 = base[64 + lane], a2 = base[128 + lane], a3 = base[192 + lane];
        ull b0 = __ballot(a0 != 0);
        ull b1 = __ballot(a1 != 0);
        ull b2 = __ballot(a2 != 0);
        ull b3 = __ballot(a3 != 0);
        if (lane < 4) {
            ull v = (lane == 0) ? b0 : ((lane == 1) ? b1 : ((lane == 2) ? b2 : b3));
            bm[(size_t)win * 4 + lane] = v;
        }
    }
}

// ---- flash18: round-10/17 proven body; partials stored as bf16 (halves the
//      flash-side partial write and merge-side read traffic; added output
//      error ~3e-5 << 1.5e-3 threshold). Plain-sum softmax
//      (|score| <= beta < 1 -> p = adj ? exp(s) : 0). ----
__global__ __launch_bounds__(256, 2) void flash18(const __hip_bfloat16* __restrict__ Qbf,
                                                  const __hip_bfloat16* __restrict__ Kbf,
                                                  const __hip_bfloat16* __restrict__ Vt,
                                                  const ull* __restrict__ bm,
                                                  __hip_bfloat16* __restrict__ Opart,
                                                  float* __restrict__ Lpart) {
    // LDS: K[2][64][128]bf16 (2x16K) | V[2][128][64]bf16 @32768 (2x16K)
    //      P: 4 waves x 2 tiles x [16][64] swizzled @65536 (16K). Total 80K.
    __shared__ char smem[81920];

    const int tid  = threadIdx.x;
    const int w    = tid >> 6;
    const int lane = tid & 63;
    const int g    = lane >> 4;
    const int ln   = lane & 15;
    const int bid  = blockIdx.x;
    const int jc   = bid & (JSPLIT - 1);
    const int rt   = bid >> 3;            // 0..63
    const int wra  = rt * 128 + w * 32;   // wave's first row (2 tiles of 16)
    const int jbase = jc * JCHUNK;
    const int lx   = ln & 7;

    s16x8 qf[2][4];
#pragma unroll
    for (int ti = 0; ti < 2; ++ti)
#pragma unroll
        for (int kt = 0; kt < 4; ++kt)
            qf[ti][kt] = *(const s16x8*)(Qbf + (size_t)(wra + ti * 16 + ln) * DIM + kt * 32 + g * 8);

    f32x4 zero = {0.f, 0.f, 0.f, 0.f};
    f32x4 acc[2][8];
#pragma unroll
    for (int ti = 0; ti < 2; ++ti)
#pragma unroll
        for (int dt = 0; dt < 8; ++dt) acc[ti][dt] = zero;
    float lr[2][4] = {{0.f, 0.f, 0.f, 0.f}, {0.f, 0.f, 0.f, 0.f}};

    char* pw = smem + 65536 + w * 4096;

    auto STAGE = [&](int jt, int b) {
        char* kb = smem + b * 16384;
        char* vb = smem + 32768 + b * 16384;
#pragma unroll
        for (int p = 0; p < 4; ++p) {
            int S = p * 256 + tid;
            int row = S >> 4, u = S & 15;
            gl_lds16((const char*)Kbf + (((size_t)(jt + row)) << 8) + ((u ^ (row & 7)) << 4),
                     kb + p * 4096 + w * 1024);
        }
#pragma unroll
        for (int p = 0; p < 4; ++p) {
            int S = p * 256 + tid;
            int row = S >> 3, u = S & 7;
            gl_lds16((const char*)Vt + (((size_t)row) << 14) + (((size_t)jt) << 1) + ((u ^ (row & 7)) << 4),
                     vb + p * 4096 + w * 1024);
        }
    };

    STAGE(jbase, 0);
    __syncthreads();
    int cur = 0;

    for (int it = 0; it < ITERS; ++it) {
        const int jt = jbase + it * KVB;

        // mask words (waited after QK issues; L2/L3-resident)
        ull mw[2][4];
#pragma unroll
        for (int ti = 0; ti < 2; ++ti)
#pragma unroll
            for (int r = 0; r < 4; ++r)
                mw[ti][r] = bm[(size_t)(wra + ti * 16 + g * 4 + r) * 128 + (jt >> 6)];
        __builtin_amdgcn_sched_barrier(0);

        // prefetch next tile into the other buffer
        STAGE(jbase + ((it + 1) & (ITERS - 1)) * KVB, cur ^ 1);

        const char* kb = smem + cur * 16384;
        const char* vb = smem + 32768 + cur * 16384;

        // QK: each kf fragment feeds both row tiles
        f32x4 s4[2][4];
#pragma unroll
        for (int ti = 0; ti < 2; ++ti)
#pragma unroll
            for (int ct = 0; ct < 4; ++ct) s4[ti][ct] = zero;
#pragma unroll
        for (int ct = 0; ct < 4; ++ct)
#pragma unroll
            for (int kt = 0; kt < 4; ++kt) {
                s16x8 kf = *(const s16x8*)(kb + (ct * 16 + ln) * 256 + (((kt * 4 + g) ^ lx) << 4));
                s4[0][ct] = __builtin_amdgcn_mfma_f32_16x16x32_bf16(qf[0][kt], kf, s4[0][ct], 0, 0, 0);
                s4[1][ct] = __builtin_amdgcn_mfma_f32_16x16x32_bf16(qf[1][kt], kf, s4[1][ct], 0, 0, 0);
            }

        // softmax-lite: p = adj ? exp(s) : 0; P -> swizzled LDS
#pragma unroll
        for (int ti = 0; ti < 2; ++ti)
#pragma unroll
            for (int r = 0; r < 4; ++r) {
                const int row = g * 4 + r;
                const int rs = row & 7;
#pragma unroll
                for (int ct = 0; ct < 4; ++ct) {
                    float p = ((mw[ti][r] >> (ct * 16 + ln)) & 1) ? __expf(s4[ti][ct][r]) : 0.f;
                    lr[ti][r] += p;
                    *(__hip_bfloat16*)(pw + ti * 2048 + row * 128 +
                                       (((ct * 2 + (ln >> 3)) ^ rs) << 4) + (ln & 7) * 2)
                        = __float2bfloat16(p);
                }
            }

        // PV: each vf fragment feeds both row tiles (same-wave LDS RAW on P)
#pragma unroll
        for (int kt2 = 0; kt2 < 2; ++kt2) {
            const int uo = ((kt2 * 4 + g) ^ lx) << 4;
            s16x8 pf0 = *(const s16x8*)(pw + ln * 128 + uo);
            s16x8 pf1 = *(const s16x8*)(pw + 2048 + ln * 128 + uo);
#pragma unroll
            for (int dt = 0; dt < 8; ++dt) {
                s16x8 vf = *(const s16x8*)(vb + (dt * 16 + ln) * 128 + uo);
                acc[0][dt] = __builtin_amdgcn_mfma_f32_16x16x32_bf16(pf0, vf, acc[0][dt], 0, 0, 0);
                acc[1][dt] = __builtin_amdgcn_mfma_f32_16x16x32_bf16(pf1, vf, acc[1][dt], 0, 0, 0);
            }
        }

        __syncthreads();   // drains STAGE(t+1) (overlapped by whole compute phase)
        cur ^= 1;
    }

    // row sums within 16-lane group
#pragma unroll
    for (int ti = 0; ti < 2; ++ti)
#pragma unroll
        for (int r = 0; r < 4; ++r) {
            lr[ti][r] += __shfl_xor(lr[ti][r], 1);
            lr[ti][r] += __shfl_xor(lr[ti][r], 2);
            lr[ti][r] += __shfl_xor(lr[ti][r], 4);
            lr[ti][r] += __shfl_xor(lr[ti][r], 8);
        }

    // write partials (bf16: halves partial traffic; error << threshold)
#pragma unroll
    for (int ti = 0; ti < 2; ++ti) {
        __hip_bfloat16* ob = Opart + ((size_t)jc * NROWS + wra + ti * 16 + g * 4) * DIM;
#pragma unroll
        for (int r = 0; r < 4; ++r)
#pragma unroll
            for (int dt = 0; dt < 8; ++dt)
                ob[(size_t)r * DIM + dt * 16 + ln] = __float2bfloat16(acc[ti][dt][r]);
        if (ln == 0) {
#pragma unroll
            for (int r = 0; r < 4; ++r)
                Lpart[(size_t)jc * NROWS + wra + ti * 16 + g * 4 + r] = lr[ti][r];
        }
    }
}

// ---- merge: out[row][d] = sum_jc Op / sum_jc L (bf16 partials, short4 loads) ----
__global__ __launch_bounds__(256) void merge18(const __hip_bfloat16* __restrict__ Opart,
                                               const float* __restrict__ Lpart,
                                               float* __restrict__ out) {
    int gid = blockIdx.x * 256 + threadIdx.x;
    int row = gid >> 5;
    int dq  = (gid & 31) * 4;
    float4 sum = {0.f, 0.f, 0.f, 0.f};
    float L = 0.f;
#pragma unroll
    for (int jc = 0; jc < JSPLIT; ++jc) {
        short4 v = *(const short4*)(Opart + ((size_t)jc * NROWS + row) * DIM + dq);
        sum.x += bf16_to_f32(v.x);
        sum.y += bf16_to_f32(v.y);
        sum.z += bf16_to_f32(v.z);
        sum.w += bf16_to_f32(v.w);
        L += Lpart[(size_t)jc * NROWS + row];
    }
    float inv = 1.0f / fmaxf(L, 1e-37f);
    float4 ov = {sum.x * inv, sum.y * inv, sum.z * inv, sum.w * inv};
    *(float4*)(out + (size_t)row * DIM + dq) = ov;
}

extern "C" void kernel_launch(void* const* d_in, const int* in_sizes, int n_in,
                              void* d_out, int out_size, void* d_ws, size_t ws_size,
                              hipStream_t stream) {
    const float* xi   = (const float*)d_in[0];
    const float* xj   = (const float*)d_in[1];
    const int*   adj  = (const int*)d_in[2];
    const float* beta = (const float*)d_in[3];
    float* out = (float*)d_out;

    char* ws = (char*)d_ws;
    __hip_bfloat16* Qbf = (__hip_bfloat16*)ws;                                    // @0,   2 MiB
    __hip_bfloat16* Kbf = (__hip_bfloat16*)(ws + (2u << 20));                     // @2M,  2 MiB
    __hip_bfloat16* Vt  = (__hip_bfloat16*)(ws + (4u << 20));                     // @4M,  2 MiB
    ull*            bm  = (ull*)(ws + (6u << 20));                                // @6M,  8 MiB
    __hip_bfloat16* Op  = (__hip_bfloat16*)(ws + (14u << 20));                    // @14M, 16 MiB
    float*          Lp  = (float*)(ws + (30u << 20));                             // @30M, 256 KiB

    hipLaunchKernelGGL(prep_all, dim3(2048), dim3(256), 0, stream, xi, xj, beta, adj, Qbf, Kbf, Vt, bm);
    hipLaunchKernelGGL(flash18, dim3(64 * JSPLIT), dim3(256), 0, stream, Qbf, Kbf, Vt, bm, Op, Lp);
    hipLaunchKernelGGL(merge18, dim3(1024), dim3(256), 0, stream, Op, Lp, out);
}